// Round 3
// baseline (122.306 us; speedup 1.0000x reference)
//
#include <hip/hip_runtime.h>

#define NROWS 16384
#define DIM   1024          // floats per row
#define MARGIN_F 1.0f
#define EPS_F 1e-6f

// ---------------- Kernel A: inverse norms (one wave per row) ----------------
// Streams the whole 64 MiB table once (re-warms the LLC after the harness's
// 268 MB poison evicted it), writes 16384 inv-norm floats.
__global__ __launch_bounds__(256) void inv_norm_kernel(
    const float* __restrict__ emb,
    float*       __restrict__ inv_norm)
{
    const int tid  = threadIdx.x;
    const int lane = tid & 63;
    const int wid  = tid >> 6;
    const int row  = blockIdx.x * 4 + wid;

    const float4* x = (const float4*)(emb + (size_t)row * DIM);
    float4 a[4];
    #pragma unroll
    for (int j = 0; j < 4; ++j) a[j] = x[lane + 64 * j];

    float s = 0.f;
    #pragma unroll
    for (int j = 0; j < 4; ++j) {
        s = fmaf(a[j].x, a[j].x, s); s = fmaf(a[j].y, a[j].y, s);
        s = fmaf(a[j].z, a[j].z, s); s = fmaf(a[j].w, a[j].w, s);
    }
    #pragma unroll
    for (int m = 1; m < 64; m <<= 1) s += __shfl_xor(s, m, 64);

    if (lane == 0) inv_norm[row] = 1.0f / fmaxf(sqrtf(s), EPS_F);
}

// ---------------- Kernel B: dot products + per-row loss ----------------
// One wave per row. d^2 = si^2*|a|^2 + sp^2*|b|^2 - 2*si*sp*(a.b)
//                       = 2 - 2*si*sp*(a.b)   (norms cancel exactly; the
// reference's +eps inside the difference contributes ~2e-6 — negligible).
// Only 2 reduction chains and ONE butterfly phase.
__global__ __launch_bounds__(256) void row_loss_kernel(
    const float* __restrict__ emb,
    const float* __restrict__ inv_norm,
    const int*   __restrict__ pos_idx,
    const int*   __restrict__ neg_idx,
    float*       __restrict__ losses)
{
    const int tid  = threadIdx.x;
    const int lane = tid & 63;
    const int wid  = tid >> 6;
    const int row  = blockIdx.x * 4 + wid;

    const int p = pos_idx[row];
    const int n = neg_idx[row];

    // broadcast scalar loads (same address across the wave -> 1 transaction)
    const float si = inv_norm[row];
    const float sp = inv_norm[p];
    const float sn = inv_norm[n];

    const float4* xi = (const float4*)(emb + (size_t)row * DIM);
    const float4* xp = (const float4*)(emb + (size_t)p   * DIM);
    const float4* xn = (const float4*)(emb + (size_t)n   * DIM);

    float4 a[4], b[4], c[4];
    #pragma unroll
    for (int j = 0; j < 4; ++j) {
        a[j] = xi[lane + 64 * j];
        b[j] = xp[lane + 64 * j];
        c[j] = xn[lane + 64 * j];
    }

    float dab = 0.f, dac = 0.f;
    #pragma unroll
    for (int j = 0; j < 4; ++j) {
        dab = fmaf(a[j].x, b[j].x, dab); dab = fmaf(a[j].y, b[j].y, dab);
        dab = fmaf(a[j].z, b[j].z, dab); dab = fmaf(a[j].w, b[j].w, dab);
        dac = fmaf(a[j].x, c[j].x, dac); dac = fmaf(a[j].y, c[j].y, dac);
        dac = fmaf(a[j].z, c[j].z, dac); dac = fmaf(a[j].w, c[j].w, dac);
    }
    #pragma unroll
    for (int m = 1; m < 64; m <<= 1) {
        dab += __shfl_xor(dab, m, 64);
        dac += __shfl_xor(dac, m, 64);
    }

    if (lane == 0) {
        float sum_p = fmaxf(2.0f - 2.0f * si * sp * dab, 0.0f);
        float sum_n = fmaxf(2.0f - 2.0f * si * sn * dac, 0.0f);
        float d_pos = sqrtf(sum_p) + EPS_F;
        float d_neg = sqrtf(sum_n) + EPS_F;
        float mq = fmaxf(MARGIN_F - d_neg, EPS_F);
        losses[row] = d_pos * d_pos + mq * mq;
    }
}

// ---------------- Kernel C: final sum ----------------
__global__ __launch_bounds__(1024) void final_reduce_kernel(
    const float* __restrict__ losses,
    float*       __restrict__ out)
{
    const int tid  = threadIdx.x;
    const int lane = tid & 63;
    const int wid  = tid >> 6;   // 16 waves

    const float4* l4 = (const float4*)losses;   // NROWS/4 = 4096 float4
    float s = 0.0f;
    #pragma unroll
    for (int j = 0; j < 4; ++j) {
        float4 v = l4[tid + 1024 * j];
        s += v.x + v.y + v.z + v.w;
    }
    #pragma unroll
    for (int m = 1; m < 64; m <<= 1) s += __shfl_xor(s, m, 64);

    __shared__ float sm[16];
    if (lane == 0) sm[wid] = s;
    __syncthreads();
    if (tid == 0) {
        float total = 0.f;
        #pragma unroll
        for (int w = 0; w < 16; ++w) total += sm[w];
        out[0] = total / (2.0f * (float)NROWS);
    }
}

extern "C" void kernel_launch(void* const* d_in, const int* in_sizes, int n_in,
                              void* d_out, int out_size, void* d_ws, size_t ws_size,
                              hipStream_t stream) {
    const float* emb = (const float*)d_in[0];
    // d_in[1] = labels (unused by the loss itself)
    const int* pos = (const int*)d_in[2];
    const int* neg = (const int*)d_in[3];

    float* inv_norm = (float*)d_ws;                 // NROWS floats
    float* losses   = (float*)d_ws + NROWS;         // NROWS floats
    float* out      = (float*)d_out;

    inv_norm_kernel<<<NROWS / 4, 256, 0, stream>>>(emb, inv_norm);
    row_loss_kernel<<<NROWS / 4, 256, 0, stream>>>(emb, inv_norm, pos, neg, losses);
    final_reduce_kernel<<<1, 1024, 0, stream>>>(losses, out);
}